// Round 1
// baseline (681.811 us; speedup 1.0000x reference)
//
#include <hip/hip_runtime.h>
#include <math.h>

// GCN 2-layer: out = A_norm(relu(A_norm(x@W1)+b1... ) )  -- see reference.
// A_norm = D^-1/2 (A+I) D^-1/2, D = in-degree incl self loop.
// N=100000, E=1600000, D_IN=128, D_H=64, D_OUT=32 (read from in_sizes).

#define THREADS 256

// ---------------- edge-index normalization ----------------
// The harness may hand us edge_index as int32 or as raw int64 (little-endian).
// If int64 with values < 2^31, the int32 view is (lo, 0) pairs: detect by
// sampling odd words. flag=1 -> int64 layout.
__global__ __launch_bounds__(THREADS) void k_detect(const int* __restrict__ idx,
                                                    int E, int* __restrict__ flag) {
    __shared__ int nz;
    if (threadIdx.x == 0) nz = 0;
    __syncthreads();
    int n = (E < 1024) ? E : 1024;
    for (int i = threadIdx.x; i < n; i += blockDim.x)
        if (idx[2 * i + 1] != 0) nz = 1;  // benign race, all write 1
    __syncthreads();
    if (threadIdx.x == 0) *flag = (nz == 0) ? 1 : 0;
}

__global__ __launch_bounds__(THREADS) void k_norm_idx(const int* __restrict__ idx, int E,
                                                      const int* __restrict__ flag,
                                                      int* __restrict__ srcn,
                                                      int* __restrict__ dstn) {
    int is64 = *flag;
    int stride = gridDim.x * blockDim.x;
    for (int e = blockIdx.x * blockDim.x + threadIdx.x; e < E; e += stride) {
        if (is64) {
            srcn[e] = idx[2 * e];
            dstn[e] = idx[2 * E + 2 * e];
        } else {
            srcn[e] = idx[e];
            dstn[e] = idx[E + e];
        }
    }
}

// ---------------- degree / norm ----------------
__global__ __launch_bounds__(THREADS) void k_deg_init(float* __restrict__ deg, int N) {
    int i = blockIdx.x * blockDim.x + threadIdx.x;
    if (i < N) deg[i] = 1.0f;  // self loop
}

__global__ __launch_bounds__(THREADS) void k_deg_count(const int* __restrict__ dst, int E,
                                                       float* __restrict__ deg) {
    int stride = gridDim.x * blockDim.x;
    for (int e = blockIdx.x * blockDim.x + threadIdx.x; e < E; e += stride)
        atomicAdd(&deg[dst[e]], 1.0f);
}

__global__ __launch_bounds__(THREADS) void k_dinv(const float* __restrict__ deg,
                                                  float* __restrict__ dinv, int N) {
    int i = blockIdx.x * blockDim.x + threadIdx.x;
    if (i < N) dinv[i] = 1.0f / sqrtf(deg[i]);  // deg >= 1 always
}

// ---------------- GEMM1: h1 = x @ W1   [N,128]@[128,64] ----------------
// 64-row x 64-col tile, K staged in two 64-wide halves. LDS 33KB.
__global__ __launch_bounds__(THREADS) void k_gemm1(const float* __restrict__ x,
                                                   const float* __restrict__ W,
                                                   float* __restrict__ h, int N) {
    __shared__ float xs[64][68];  // [row][k]; stride 68 == 4 mod 32 -> conflict-free reads
    __shared__ float ws[64][64];  // [k][col]
    const int tid = threadIdx.x;
    const int brow = blockIdx.x * 64;
    const int lane = tid & 63, wv = tid >> 6;
    const int jc = (lane & 15) << 2;          // col base 0..60
    const int rb = (lane >> 4) + (wv << 2);   // 0..15; rows rb+16i
    float4 acc[4];
    acc[0] = acc[1] = acc[2] = acc[3] = make_float4(0.f, 0.f, 0.f, 0.f);

    for (int kt = 0; kt < 128; kt += 64) {
        // stage x tile: 64 rows x 64 k (1024 float4)
        for (int f = tid; f < 64 * 16; f += THREADS) {
            int r = f >> 4, k4 = (f & 15) << 2;
            int row = brow + r;
            float4 v = make_float4(0.f, 0.f, 0.f, 0.f);
            if (row < N) v = *(const float4*)&x[(size_t)row * 128 + kt + k4];
            *(float4*)&xs[r][k4] = v;
        }
        // stage W half: 64 k x 64 cols
        for (int f = tid; f < 64 * 16; f += THREADS) {
            int k = f >> 4, c4 = (f & 15) << 2;
            *(float4*)&ws[k][c4] = *(const float4*)&W[(size_t)(kt + k) * 64 + c4];
        }
        __syncthreads();
#pragma unroll
        for (int k = 0; k < 64; k += 4) {
            float4 a[4], b[4];
#pragma unroll
            for (int i = 0; i < 4; ++i) a[i] = *(const float4*)&xs[rb + (i << 4)][k];
#pragma unroll
            for (int kk = 0; kk < 4; ++kk) b[kk] = *(const float4*)&ws[k + kk][jc];
#pragma unroll
            for (int i = 0; i < 4; ++i) {
                const float* ai = (const float*)&a[i];
#pragma unroll
                for (int kk = 0; kk < 4; ++kk) {
                    float av = ai[kk];
                    acc[i].x += av * b[kk].x;
                    acc[i].y += av * b[kk].y;
                    acc[i].z += av * b[kk].z;
                    acc[i].w += av * b[kk].w;
                }
            }
        }
        __syncthreads();
    }
#pragma unroll
    for (int i = 0; i < 4; ++i) {
        int row = brow + rb + (i << 4);
        if (row < N) *(float4*)&h[(size_t)row * 64 + jc] = acc[i];
    }
}

// ---------------- layer-1 scatter ----------------
// init: self-loop contribution + bias (pre-relu buffer)
__global__ __launch_bounds__(THREADS) void k_agg1_init(const float* __restrict__ h,
                                                       const float* __restrict__ dinv,
                                                       const float* __restrict__ b,
                                                       float* __restrict__ out, int N) {
    int stride = gridDim.x * blockDim.x;
    int total = N * 16;  // float4 groups of 64-wide rows
    for (int i = blockIdx.x * blockDim.x + threadIdx.x; i < total; i += stride) {
        int n = i >> 4, c4 = (i & 15) << 2;
        float di = dinv[n];
        float w = di * di;
        float4 v = *(const float4*)&h[(size_t)n * 64 + c4];
        float4 bb = *(const float4*)&b[c4];
        v.x = v.x * w + bb.x; v.y = v.y * w + bb.y;
        v.z = v.z * w + bb.z; v.w = v.w * w + bb.w;
        *(float4*)&out[(size_t)n * 64 + c4] = v;
    }
}

__global__ __launch_bounds__(THREADS) void k_agg1(const int* __restrict__ src,
                                                  const int* __restrict__ dst,
                                                  const float* __restrict__ dinv,
                                                  const float* __restrict__ h,
                                                  float* __restrict__ out, int E) {
    int total = E << 6;  // 64 lanes per edge; 102.4M < 2^31
    int stride = gridDim.x * blockDim.x;
    for (int i = blockIdx.x * blockDim.x + threadIdx.x; i < total; i += stride) {
        int e = i >> 6, l = i & 63;
        int s = src[e], d = dst[e];
        float w = dinv[s] * dinv[d];
        atomicAdd(&out[(size_t)d * 64 + l], h[(size_t)s * 64 + l] * w);
    }
}

// ---------------- GEMM2: h2 = relu(o1) @ W2  [N,64]@[64,32] ----------------
__global__ __launch_bounds__(THREADS) void k_gemm2(const float* __restrict__ a_in,
                                                   const float* __restrict__ W,
                                                   float* __restrict__ h, int N) {
    __shared__ float xs[128][68];
    __shared__ float ws[64][32];
    const int tid = threadIdx.x;
    const int brow = blockIdx.x * 128;
    // stage relu(a): 128 rows x 64 k (2048 float4)
    for (int f = tid; f < 128 * 16; f += THREADS) {
        int r = f >> 4, k4 = (f & 15) << 2;
        int row = brow + r;
        float4 v = make_float4(0.f, 0.f, 0.f, 0.f);
        if (row < N) {
            v = *(const float4*)&a_in[(size_t)row * 64 + k4];
            v.x = fmaxf(v.x, 0.f); v.y = fmaxf(v.y, 0.f);
            v.z = fmaxf(v.z, 0.f); v.w = fmaxf(v.w, 0.f);
        }
        *(float4*)&xs[r][k4] = v;
    }
    for (int f = tid; f < 64 * 8; f += THREADS) {
        int k = f >> 3, c4 = (f & 7) << 2;
        *(float4*)&ws[k][c4] = *(const float4*)&W[(size_t)k * 32 + c4];
    }
    __syncthreads();
    const int lane = tid & 63, wv = tid >> 6;
    const int jc = (lane & 7) << 2;          // 0..28
    const int rb = (lane >> 3) + (wv << 3);  // 0..31; rows rb+32i
    float4 acc[4];
    acc[0] = acc[1] = acc[2] = acc[3] = make_float4(0.f, 0.f, 0.f, 0.f);
#pragma unroll
    for (int k = 0; k < 64; k += 4) {
        float4 a[4], b[4];
#pragma unroll
        for (int i = 0; i < 4; ++i) a[i] = *(const float4*)&xs[rb + (i << 5)][k];
#pragma unroll
        for (int kk = 0; kk < 4; ++kk) b[kk] = *(const float4*)&ws[k + kk][jc];
#pragma unroll
        for (int i = 0; i < 4; ++i) {
            const float* ai = (const float*)&a[i];
#pragma unroll
            for (int kk = 0; kk < 4; ++kk) {
                float av = ai[kk];
                acc[i].x += av * b[kk].x;
                acc[i].y += av * b[kk].y;
                acc[i].z += av * b[kk].z;
                acc[i].w += av * b[kk].w;
            }
        }
    }
#pragma unroll
    for (int i = 0; i < 4; ++i) {
        int row = brow + rb + (i << 5);
        if (row < N) *(float4*)&h[(size_t)row * 32 + jc] = acc[i];
    }
}

// ---------------- layer-2 scatter (into d_out) ----------------
__global__ __launch_bounds__(THREADS) void k_agg2_init(const float* __restrict__ h,
                                                       const float* __restrict__ dinv,
                                                       const float* __restrict__ b,
                                                       float* __restrict__ out, int N) {
    int stride = gridDim.x * blockDim.x;
    int total = N * 8;  // float4 groups of 32-wide rows
    for (int i = blockIdx.x * blockDim.x + threadIdx.x; i < total; i += stride) {
        int n = i >> 3, c4 = (i & 7) << 2;
        float di = dinv[n];
        float w = di * di;
        float4 v = *(const float4*)&h[(size_t)n * 32 + c4];
        float4 bb = *(const float4*)&b[c4];
        v.x = v.x * w + bb.x; v.y = v.y * w + bb.y;
        v.z = v.z * w + bb.z; v.w = v.w * w + bb.w;
        *(float4*)&out[(size_t)n * 32 + c4] = v;
    }
}

__global__ __launch_bounds__(THREADS) void k_agg2(const int* __restrict__ src,
                                                  const int* __restrict__ dst,
                                                  const float* __restrict__ dinv,
                                                  const float* __restrict__ h,
                                                  float* __restrict__ out, int E) {
    int total = E << 5;  // 32 lanes per edge; 51.2M
    int stride = gridDim.x * blockDim.x;
    for (int i = blockIdx.x * blockDim.x + threadIdx.x; i < total; i += stride) {
        int e = i >> 5, l = i & 31;
        int s = src[e], d = dst[e];
        float w = dinv[s] * dinv[d];
        atomicAdd(&out[(size_t)d * 32 + l], h[(size_t)s * 32 + l] * w);
    }
}

extern "C" void kernel_launch(void* const* d_in, const int* in_sizes, int n_in,
                              void* d_out, int out_size, void* d_ws, size_t ws_size,
                              hipStream_t stream) {
    const int N = in_sizes[0] / 128;
    const int E = in_sizes[1] / 2;
    const float* x  = (const float*)d_in[0];
    const int*   ei = (const int*)d_in[1];
    const float* W1 = (const float*)d_in[2];
    const float* b1 = (const float*)d_in[3];
    const float* W2 = (const float*)d_in[4];
    const float* b2 = (const float*)d_in[5];
    float* out = (float*)d_out;

    // workspace carve (fp32): deg N | dinv N | h1 N*64 | o1 N*64 | h2 N*32 | srcn E | dstn E | flag
    float* deg  = (float*)d_ws;
    float* dinv = deg + N;
    float* h1   = dinv + N;
    float* o1   = h1 + (size_t)N * 64;
    float* h2   = o1 + (size_t)N * 64;
    int*   srcn = (int*)(h2 + (size_t)N * 32);
    int*   dstn = srcn + E;
    int*   flag = dstn + E;

    k_detect<<<1, THREADS, 0, stream>>>(ei, E, flag);
    k_norm_idx<<<2048, THREADS, 0, stream>>>(ei, E, flag, srcn, dstn);
    k_deg_init<<<(N + THREADS - 1) / THREADS, THREADS, 0, stream>>>(deg, N);
    k_deg_count<<<2048, THREADS, 0, stream>>>(dstn, E, deg);
    k_dinv<<<(N + THREADS - 1) / THREADS, THREADS, 0, stream>>>(deg, dinv, N);

    k_gemm1<<<(N + 63) / 64, THREADS, 0, stream>>>(x, W1, h1, N);
    k_agg1_init<<<4096, THREADS, 0, stream>>>(h1, dinv, b1, o1, N);
    k_agg1<<<4096, THREADS, 0, stream>>>(srcn, dstn, dinv, h1, o1, E);

    k_gemm2<<<(N + 127) / 128, THREADS, 0, stream>>>(o1, W2, h2, N);
    k_agg2_init<<<2048, THREADS, 0, stream>>>(h2, dinv, b2, out, N);
    k_agg2<<<4096, THREADS, 0, stream>>>(srcn, dstn, dinv, h2, out, E);
}

// Round 2
// 462.992 us; speedup vs baseline: 1.4726x; 1.4726x over previous
//
#include <hip/hip_runtime.h>
#include <math.h>

// GCN 2-layer, CSR-based aggregation (no fp atomics).
// out = Anorm( relu(Anorm(x@W1)+b1) @ W2 ) + b2,  Anorm = D^-1/2 (A+I) D^-1/2.
// Fold dinv[src] into GEMM epilogue: h1s = dinv[row]*(x@W1); then
// o1[n] = dinv[n]*(sum_{src in N(n)} h1s[src] + h1s[n]) + b1.

#define THREADS 256

// ---------------- edge-index dtype detection ----------------
__global__ __launch_bounds__(THREADS) void k_detect(const int* __restrict__ idx,
                                                    int E, int* __restrict__ flag) {
    __shared__ int nz;
    if (threadIdx.x == 0) nz = 0;
    __syncthreads();
    int n = (E < 1024) ? E : 1024;
    for (int i = threadIdx.x; i < n; i += blockDim.x)
        if (idx[2 * i + 1] != 0) nz = 1;  // benign race
    __syncthreads();
    if (threadIdx.x == 0) *flag = (nz == 0) ? 1 : 0;  // 1 -> int64 layout
}

__global__ __launch_bounds__(THREADS) void k_zero_i(int* __restrict__ p, int n) {
    int i = blockIdx.x * blockDim.x + threadIdx.x;
    if (i < n) p[i] = 0;
}

// dstn[e] + int histogram of in-degree (no self loop yet)
__global__ __launch_bounds__(THREADS) void k_norm_hist(const int* __restrict__ idx, int E,
                                                       const int* __restrict__ flag,
                                                       int* __restrict__ dstn,
                                                       int* __restrict__ degi) {
    int is64 = *flag;
    int stride = gridDim.x * blockDim.x;
    for (int e = blockIdx.x * blockDim.x + threadIdx.x; e < E; e += stride) {
        int d = is64 ? idx[2 * E + 2 * e] : idx[E + e];
        dstn[e] = d;
        atomicAdd(&degi[d], 1);
    }
}

__global__ __launch_bounds__(THREADS) void k_dinv(const int* __restrict__ degi,
                                                  float* __restrict__ dinv, int N) {
    int i = blockIdx.x * blockDim.x + threadIdx.x;
    if (i < N) dinv[i] = rsqrtf((float)(degi[i] + 1));  // +1 self loop
}

// ---------------- prefix scan (3 kernels, CHUNK=1024/block) ----------------
__global__ __launch_bounds__(THREADS) void k_blk_sum(const int* __restrict__ degi,
                                                     int* __restrict__ blksum, int N) {
    __shared__ int sm[4];
    int base = blockIdx.x * 1024 + threadIdx.x * 4;
    int s = 0;
#pragma unroll
    for (int k = 0; k < 4; ++k) { int i = base + k; if (i < N) s += degi[i]; }
    int lane = threadIdx.x & 63, w = threadIdx.x >> 6;
#pragma unroll
    for (int off = 32; off; off >>= 1) s += __shfl_down(s, off);
    if (lane == 0) sm[w] = s;
    __syncthreads();
    if (threadIdx.x == 0) blksum[blockIdx.x] = sm[0] + sm[1] + sm[2] + sm[3];
}

__global__ __launch_bounds__(64) void k_scan_blk(const int* __restrict__ blksum,
                                                 int* __restrict__ blkoff, int nblk) {
    int lane = threadIdx.x;
    int carry = 0;
    for (int base = 0; base < nblk; base += 64) {
        int i = base + lane;
        int raw = (i < nblk) ? blksum[i] : 0;
        int v = raw;
#pragma unroll
        for (int off = 1; off < 64; off <<= 1) {
            int u = __shfl_up(v, off);
            if (lane >= off) v += u;
        }
        if (i < nblk) blkoff[i] = v - raw + carry;
        carry += __shfl(v, 63);
    }
}

__global__ __launch_bounds__(THREADS) void k_scan_write(const int* __restrict__ degi,
                                                        const int* __restrict__ blkoff,
                                                        int* __restrict__ row_ptr,
                                                        int* __restrict__ cursor, int N) {
    __shared__ int wsum[4];
    int t = threadIdx.x;
    int base = blockIdx.x * 1024 + t * 4;
    int d[4]; int s = 0;
#pragma unroll
    for (int k = 0; k < 4; ++k) { int i = base + k; d[k] = (i < N) ? degi[i] : 0; s += d[k]; }
    int lane = t & 63, w = t >> 6;
    int v = s;
#pragma unroll
    for (int off = 1; off < 64; off <<= 1) {
        int u = __shfl_up(v, off);
        if (lane >= off) v += u;
    }
    if (lane == 63) wsum[w] = v;
    __syncthreads();
    int wadd = 0;
#pragma unroll
    for (int k = 0; k < 4; ++k) if (k < w) wadd += wsum[k];
    int excl = v - s + wadd + blkoff[blockIdx.x];
#pragma unroll
    for (int k = 0; k < 4; ++k) {
        int i = base + k;
        if (i < N) { row_ptr[i] = excl; cursor[i] = excl; }
        excl += d[k];
    }
}

__global__ __launch_bounds__(THREADS) void k_scatter(const int* __restrict__ idx, int E,
                                                     const int* __restrict__ flag,
                                                     const int* __restrict__ dstn,
                                                     int* __restrict__ cursor,
                                                     int* __restrict__ csr_src) {
    int is64 = *flag;
    int stride = gridDim.x * blockDim.x;
    for (int e = blockIdx.x * blockDim.x + threadIdx.x; e < E; e += stride) {
        int s = is64 ? idx[2 * e] : idx[e];
        int d = dstn[e];
        int p = atomicAdd(&cursor[d], 1);
        csr_src[p] = s;
    }
}

// ---------------- GEMM1: h1s = dinv[row] * (x @ W1)   [N,128]@[128,64] ----------------
__global__ __launch_bounds__(THREADS) void k_gemm1(const float* __restrict__ x,
                                                   const float* __restrict__ W,
                                                   const float* __restrict__ dinv,
                                                   float* __restrict__ h, int N) {
    __shared__ float xs[64][68];
    __shared__ float ws[64][64];
    const int tid = threadIdx.x;
    const int brow = blockIdx.x * 64;
    const int lane = tid & 63, wv = tid >> 6;
    const int jc = (lane & 15) << 2;
    const int rb = (lane >> 4) + (wv << 2);
    float4 acc[4];
    acc[0] = acc[1] = acc[2] = acc[3] = make_float4(0.f, 0.f, 0.f, 0.f);

    for (int kt = 0; kt < 128; kt += 64) {
        for (int f = tid; f < 64 * 16; f += THREADS) {
            int r = f >> 4, k4 = (f & 15) << 2;
            int row = brow + r;
            float4 v = make_float4(0.f, 0.f, 0.f, 0.f);
            if (row < N) v = *(const float4*)&x[(size_t)row * 128 + kt + k4];
            *(float4*)&xs[r][k4] = v;
        }
        for (int f = tid; f < 64 * 16; f += THREADS) {
            int k = f >> 4, c4 = (f & 15) << 2;
            *(float4*)&ws[k][c4] = *(const float4*)&W[(size_t)(kt + k) * 64 + c4];
        }
        __syncthreads();
#pragma unroll
        for (int k = 0; k < 64; k += 4) {
            float4 a[4], b[4];
#pragma unroll
            for (int i = 0; i < 4; ++i) a[i] = *(const float4*)&xs[rb + (i << 4)][k];
#pragma unroll
            for (int kk = 0; kk < 4; ++kk) b[kk] = *(const float4*)&ws[k + kk][jc];
#pragma unroll
            for (int i = 0; i < 4; ++i) {
                const float* ai = (const float*)&a[i];
#pragma unroll
                for (int kk = 0; kk < 4; ++kk) {
                    float av = ai[kk];
                    acc[i].x += av * b[kk].x;
                    acc[i].y += av * b[kk].y;
                    acc[i].z += av * b[kk].z;
                    acc[i].w += av * b[kk].w;
                }
            }
        }
        __syncthreads();
    }
#pragma unroll
    for (int i = 0; i < 4; ++i) {
        int row = brow + rb + (i << 4);
        if (row < N) {
            float dn = dinv[row];
            acc[i].x *= dn; acc[i].y *= dn; acc[i].z *= dn; acc[i].w *= dn;
            *(float4*)&h[(size_t)row * 64 + jc] = acc[i];
        }
    }
}

// ---------------- layer-1 aggregation: one wave per node, 64 feats ----------------
__global__ __launch_bounds__(THREADS) void k_agg1_csr(const int* __restrict__ row_ptr,
                                                      const int* __restrict__ degi,
                                                      const int* __restrict__ csr_src,
                                                      const float* __restrict__ dinv,
                                                      const float* __restrict__ h1s,
                                                      const float* __restrict__ b1,
                                                      float* __restrict__ o1, int N) {
    int wid = (blockIdx.x * blockDim.x + threadIdx.x) >> 6;
    int lane = threadIdx.x & 63;
    if (wid >= N) return;
    int j = row_ptr[wid];
    int end = j + degi[wid];
    float acc = 0.f;
    for (; j + 1 < end; j += 2) {
        int s0 = csr_src[j], s1 = csr_src[j + 1];
        float v0 = h1s[(size_t)s0 * 64 + lane];
        float v1 = h1s[(size_t)s1 * 64 + lane];
        acc += v0 + v1;
    }
    if (j < end) acc += h1s[(size_t)csr_src[j] * 64 + lane];
    float dn = dinv[wid];
    o1[(size_t)wid * 64 + lane] = dn * (acc + h1s[(size_t)wid * 64 + lane]) + b1[lane];
}

// ---------------- GEMM2: h2s = dinv[row] * (relu(o1) @ W2)  [N,64]@[64,32] ----------------
__global__ __launch_bounds__(THREADS) void k_gemm2(const float* __restrict__ a_in,
                                                   const float* __restrict__ W,
                                                   const float* __restrict__ dinv,
                                                   float* __restrict__ h, int N) {
    __shared__ float xs[128][68];
    __shared__ float ws[64][32];
    const int tid = threadIdx.x;
    const int brow = blockIdx.x * 128;
    for (int f = tid; f < 128 * 16; f += THREADS) {
        int r = f >> 4, k4 = (f & 15) << 2;
        int row = brow + r;
        float4 v = make_float4(0.f, 0.f, 0.f, 0.f);
        if (row < N) {
            v = *(const float4*)&a_in[(size_t)row * 64 + k4];
            v.x = fmaxf(v.x, 0.f); v.y = fmaxf(v.y, 0.f);
            v.z = fmaxf(v.z, 0.f); v.w = fmaxf(v.w, 0.f);
        }
        *(float4*)&xs[r][k4] = v;
    }
    for (int f = tid; f < 64 * 8; f += THREADS) {
        int k = f >> 3, c4 = (f & 7) << 2;
        *(float4*)&ws[k][c4] = *(const float4*)&W[(size_t)k * 32 + c4];
    }
    __syncthreads();
    const int lane = tid & 63, wv = tid >> 6;
    const int jc = (lane & 7) << 2;
    const int rb = (lane >> 3) + (wv << 3);
    float4 acc[4];
    acc[0] = acc[1] = acc[2] = acc[3] = make_float4(0.f, 0.f, 0.f, 0.f);
#pragma unroll
    for (int k = 0; k < 64; k += 4) {
        float4 a[4], b[4];
#pragma unroll
        for (int i = 0; i < 4; ++i) a[i] = *(const float4*)&xs[rb + (i << 5)][k];
#pragma unroll
        for (int kk = 0; kk < 4; ++kk) b[kk] = *(const float4*)&ws[k + kk][jc];
#pragma unroll
        for (int i = 0; i < 4; ++i) {
            const float* ai = (const float*)&a[i];
#pragma unroll
            for (int kk = 0; kk < 4; ++kk) {
                float av = ai[kk];
                acc[i].x += av * b[kk].x;
                acc[i].y += av * b[kk].y;
                acc[i].z += av * b[kk].z;
                acc[i].w += av * b[kk].w;
            }
        }
    }
#pragma unroll
    for (int i = 0; i < 4; ++i) {
        int row = brow + rb + (i << 5);
        if (row < N) {
            float dn = dinv[row];
            acc[i].x *= dn; acc[i].y *= dn; acc[i].z *= dn; acc[i].w *= dn;
            *(float4*)&h[(size_t)row * 32 + jc] = acc[i];
        }
    }
}

// ---------------- layer-2 aggregation: one wave per node, 32 feats, 2 nbrs/iter ----------------
__global__ __launch_bounds__(THREADS) void k_agg2_csr(const int* __restrict__ row_ptr,
                                                      const int* __restrict__ degi,
                                                      const int* __restrict__ csr_src,
                                                      const float* __restrict__ dinv,
                                                      const float* __restrict__ h2s,
                                                      const float* __restrict__ b2,
                                                      float* __restrict__ out, int N) {
    int wid = (blockIdx.x * blockDim.x + threadIdx.x) >> 6;
    int lane = threadIdx.x & 63;
    if (wid >= N) return;
    int half = lane >> 5, f = lane & 31;
    int start = row_ptr[wid];
    int end = start + degi[wid];
    float acc = 0.f;
    for (int j = start + half; j < end; j += 2) {
        int s = csr_src[j];
        acc += h2s[(size_t)s * 32 + f];
    }
    acc += __shfl_xor(acc, 32);  // combine halves
    if (half == 0) {
        float dn = dinv[wid];
        out[(size_t)wid * 32 + f] = dn * (acc + h2s[(size_t)wid * 32 + f]) + b2[f];
    }
}

extern "C" void kernel_launch(void* const* d_in, const int* in_sizes, int n_in,
                              void* d_out, int out_size, void* d_ws, size_t ws_size,
                              hipStream_t stream) {
    const int N = in_sizes[0] / 128;
    const int E = in_sizes[1] / 2;
    const float* x  = (const float*)d_in[0];
    const int*   ei = (const int*)d_in[1];
    const float* W1 = (const float*)d_in[2];
    const float* b1 = (const float*)d_in[3];
    const float* W2 = (const float*)d_in[4];
    const float* b2 = (const float*)d_in[5];
    float* out = (float*)d_out;

    const int NBLK = (N + 1023) / 1024;

    // workspace carve
    float* dinv   = (float*)d_ws;                 // N
    float* h1s    = dinv + N;                     // N*64
    float* o1     = h1s + (size_t)N * 64;         // N*64
    float* h2s    = o1 + (size_t)N * 64;          // N*32
    int*   degi   = (int*)(h2s + (size_t)N * 32); // N
    int*   row_ptr= degi + N;                     // N
    int*   cursor = row_ptr + N;                  // N
    int*   dstn   = cursor + N;                   // E
    int*   csr_src= dstn + E;                     // E
    int*   blksum = csr_src + E;                  // NBLK
    int*   blkoff = blksum + NBLK;                // NBLK
    int*   flag   = blkoff + NBLK;                // 1

    k_detect<<<1, THREADS, 0, stream>>>(ei, E, flag);
    k_zero_i<<<(N + THREADS - 1) / THREADS, THREADS, 0, stream>>>(degi, N);
    k_norm_hist<<<2048, THREADS, 0, stream>>>(ei, E, flag, dstn, degi);
    k_dinv<<<(N + THREADS - 1) / THREADS, THREADS, 0, stream>>>(degi, dinv, N);

    k_blk_sum<<<NBLK, THREADS, 0, stream>>>(degi, blksum, N);
    k_scan_blk<<<1, 64, 0, stream>>>(blksum, blkoff, NBLK);
    k_scan_write<<<NBLK, THREADS, 0, stream>>>(degi, blkoff, row_ptr, cursor, N);
    k_scatter<<<2048, THREADS, 0, stream>>>(ei, E, flag, dstn, cursor, csr_src);

    k_gemm1<<<(N + 63) / 64, THREADS, 0, stream>>>(x, W1, dinv, h1s, N);
    k_agg1_csr<<<(N + 3) / 4, THREADS, 0, stream>>>(row_ptr, degi, csr_src, dinv, h1s, b1, o1, N);

    k_gemm2<<<(N + 127) / 128, THREADS, 0, stream>>>(o1, W2, dinv, h2s, N);
    k_agg2_csr<<<(N + 3) / 4, THREADS, 0, stream>>>(row_ptr, degi, csr_src, dinv, h2s, b2, out, N);
}